// Round 7
// baseline (220.445 us; speedup 1.0000x reference)
//
#include <hip/hip_runtime.h>
#include <cmath>

// Outputs concatenated flat (all float32):
//   [0)      N*N*3 : dxyz_m
//   [N*N*3)  N*N   : buckets
//   [N*N*4)  N*N   : dscanid
//   [N*N*5)  N*N   : mask
//
// R7 = resubmission of R6 (container infra failure, kernel never ran).
// R6 = R5 (register-resident j, no barriers, II=4) with the write phase
// rebuilt to be structurally identical to the 6.6 TB/s rocclr fill:
//   - EVERY global store is a wave-contiguous dwordx4 (16 full 64B lines),
//     via wave-local LDS transposes for all four outputs (not just dxyz).
//   - XCD-bijective block swizzle: each XCD writes contiguous regions.
// Testing the theory that the kernel's ~2.8 TB/s effective write rate comes
// from the write path (partial-width stores / scattered frontier), e.g. RFO.

#define TPB 256   // threads per block (4 waves)
#define JB  1024  // j's per block
#define II  4     // i-rows per block -> 2304 blocks (divisible by 8 XCDs)
#define NXCD 8

typedef float f32x4 __attribute__((ext_vector_type(4)));

__device__ __forceinline__ float bucket_base(float v) {
    // x = v / RES (RES=0.5 -> exact *2)
    const float x  = v * 2.0f;
    const float xa = fabsf(x);
    if (xa <= 2.0f) {
        // round-half-to-even like jnp.round
        return 8.0f + rintf(x);
    }
    // log path only when needed (xa>2 => x != 0)
    const float lr = logf(fmaxf(xa, 1e-6f) * 0.5f) / 2.0794415416798357f; // /log(8)
    const float sup = fminf(rintf(2.0f - 6.0f * lr), 8.0f);
    return 8.0f + ((x > 0.0f) ? sup : -sup);
}

__global__ __launch_bounds__(256) void pair_kernel(
    const float* __restrict__ xyz, const int* __restrict__ grid,
    float* __restrict__ out, int N) {
#pragma clang fp contract(off)
    // Wave-local transpose staging; each wave touches only its own quadrant,
    // same-wave DS ordering -> no __syncthreads anywhere. 24 KB total.
    __shared__ float s_st[3 * JB];  // dxyz
    __shared__ float s_b[JB];       // buckets
    __shared__ float s_d[JB];       // dscanid
    __shared__ float s_m[JB];       // mask

    const int tid = threadIdx.x;
    const int w   = tid >> 6;   // wave id within block
    const int l   = tid & 63;   // lane
    const int jw0 = 256 * w;    // wave owns j-local [jw0, jw0+256)

    // ---- XCD-bijective swizzle (nwg = 2304 = 8 * 288) ----
    // HW maps original flat id o -> XCD (o % 8); remap so each XCD gets a
    // contiguous chunk of the (i,j) work space -> contiguous write frontier.
    const int nwg = gridDim.x * gridDim.y;
    int bid = blockIdx.y * gridDim.x + blockIdx.x;
    const int cpx = nwg / NXCD;
    bid = (bid % NXCD) * cpx + bid / NXCD;
    const int J0 = (bid % gridDim.x) * JB;
    const int I0 = (bid / gridDim.x) * II;

    // ---- One-time per block: this thread's 4 j's -> registers ----
    float jx[4], jy[4], jz[4];
    int   jbat[4], jblk[4], jc0[4], jc1[4], jc2[4], xcj[4], ycj[4];
#pragma unroll
    for (int k = 0; k < 4; ++k) {
        const int j = J0 + jw0 + 64 * k + l;
        jx[k]   = xyz[3 * j + 0];
        jy[k]   = xyz[3 * j + 1];
        jz[k]   = xyz[3 * j + 2];
        jbat[k] = grid[5 * j + 0];
        jblk[k] = grid[5 * j + 1];
        jc0[k]  = grid[5 * j + 2];
        jc1[k]  = grid[5 * j + 3];
        jc2[k]  = grid[5 * j + 4];
        xcj[k]  = (int)ceilf(jx[k] / 3.0f);
        ycj[k]  = (int)ceilf(jy[k] / 3.0f);
    }

    const size_t NN = (size_t)N * (size_t)N;

    for (int ii = 0; ii < II; ++ii) {
        const int i = I0 + ii;

        // i-side is block-uniform -> scalar loads
        const float xi = xyz[3 * i + 0];
        const float yi = xyz[3 * i + 1];
        const float zi = xyz[3 * i + 2];
        const int bat_i = grid[5 * i + 0];
        const int blk_i = grid[5 * i + 1];
        const int c0i = grid[5 * i + 2];
        const int c1i = grid[5 * i + 3];
        const int c2i = grid[5 * i + 4];
        const int xci = (int)ceilf(xi / 3.0f);
        const int yci = (int)ceilf(yi / 3.0f);
        const int scan_i = blk_i >> 1;

        float dxm[4], dym[4], dzm[4];
        bool  mk[4];
        bool  any = false;
#pragma unroll
        for (int k = 0; k < 4; ++k) {
            const float dx = xi - jx[k];
            const float dy = yi - jy[k];
            const float dz = zi - jz[k];
            const bool batch_eq = (bat_i == jbat[k]);
            const bool block_le = (blk_i <= jblk[k]);
            const int  cadj = max(max(abs(c0i - jc0[k]), abs(c1i - jc1[k])),
                                  abs(c2i - jc2[k]));
            const bool forcekeep = (cadj <= 1) && (blk_i == jblk[k]);
            const bool keep_coarse =
                max(abs(xci - xcj[k]), abs(yci - ycj[k])) <= 1;
            const float d2 = dx * dx + dy * dy + dz * dz; // contract(off)
            const bool keepr = (d2 <= 9.0f);
            const bool m = batch_eq && block_le &&
                           (forcekeep || keep_coarse) && (forcekeep || keepr);
            mk[k] = m;
            any |= m;
            dxm[k] = m ? dx : 0.0f;
            dym[k] = m ? dy : 0.0f;
            dzm[k] = m ? dz : 0.0f;
        }

        const size_t rowbase = (size_t)i * (size_t)N + (size_t)J0;
        // wave's spans are 1024B-aligned (rowbase, jw0 multiples of 256)
        f32x4* __restrict__ od4 =
            reinterpret_cast<f32x4*>(out + 3 * (rowbase + (size_t)jw0));
        f32x4* __restrict__ ob4 =
            reinterpret_cast<f32x4*>(out + NN * 3 + rowbase + (size_t)jw0);
        f32x4* __restrict__ os4 =
            reinterpret_cast<f32x4*>(out + NN * 4 + rowbase + (size_t)jw0);
        f32x4* __restrict__ om4 =
            reinterpret_cast<f32x4*>(out + NN * 5 + rowbase + (size_t)jw0);

        // ---- Wave-uniform fast path: whole wave empty -> packed zeros ----
        if (__ballot(any ? 1 : 0) == 0ULL) {
            const f32x4 z4 = {0.0f, 0.0f, 0.0f, 0.0f};
#pragma unroll
            for (int p = 0; p < 3; ++p) od4[64 * p + l] = z4;
            ob4[l] = z4;
            os4[l] = z4;
            om4[l] = z4;
            continue;
        }

        // ---- Slow path: stage ALL outputs in wave-local LDS ----
#pragma unroll
        for (int k = 0; k < 4; ++k) {
            const int jl = jw0 + 64 * k + l;
            float b = 0.0f, d = 0.0f, mvf = 0.0f;
            if (mk[k]) {
                const float b0 = bucket_base(dxm[k]);
                const float b1 = bucket_base(dym[k]);
                const float b2 = bucket_base(dzm[k]);
                const float bsum = (289.0f * b0 + 17.0f * b1) + b2; // exact ints
                b   = (float)(int)bsum;
                d   = (float)((jblk[k] >> 1) - scan_i);
                mvf = 1.0f;
            }
            s_b[jl] = b;                 // stride-4B across lanes: conflict-free
            s_d[jl] = d;
            s_m[jl] = mvf;
            s_st[3 * jl + 0] = dxm[k];   // stride-12B: gcd(3,32)=1, conflict-free
            s_st[3 * jl + 1] = dym[k];
            s_st[3 * jl + 2] = dzm[k];
        }

        // Transposed readback -> EVERY global store is a wave-contiguous
        // 1024B dwordx4 (16 full 64B lines per instruction), like the fill.
        // Same-wave DS ordering (lgkmcnt) -> no barrier needed.
        const f32x4* st4 = reinterpret_cast<const f32x4*>(s_st + 3 * jw0);
        const f32x4* b4  = reinterpret_cast<const f32x4*>(s_b + jw0);
        const f32x4* d4  = reinterpret_cast<const f32x4*>(s_d + jw0);
        const f32x4* m4  = reinterpret_cast<const f32x4*>(s_m + jw0);
#pragma unroll
        for (int p = 0; p < 3; ++p) od4[64 * p + l] = st4[64 * p + l];
        ob4[l] = b4[l];
        os4[l] = d4[l];
        om4[l] = m4[l];
    }
}

extern "C" void kernel_launch(void* const* d_in, const int* in_sizes, int n_in,
                              void* d_out, int out_size, void* d_ws, size_t ws_size,
                              hipStream_t stream) {
    const float* xyz  = (const float*)d_in[0];
    const int*   grid = (const int*)d_in[1];
    float*       out  = (float*)d_out;
    const int N = in_sizes[0] / 3; // xyz is (N,3); N=3072

    dim3 gdim(N / JB, N / II, 1); // (3, 768) -> 2304 blocks = 8 * 288
    pair_kernel<<<gdim, dim3(TPB, 1, 1), 0, stream>>>(xyz, grid, out, N);
}